// Round 1
// baseline (402.982 us; speedup 1.0000x reference)
//
#include <hip/hip_runtime.h>
#include <math.h>

#define N_NODES 50000
#define N_EDGES 1000000
#define CCH     32
#define ROW     288           // 32 + 96 + 160
#define SCAN_BLOCKS 196       // ceil(50000/256)

// ---------------------------------------------------------------------------
// K1: degree histogram over receivers.
// ---------------------------------------------------------------------------
__global__ __launch_bounds__(256) void hist_kernel(
    const int* __restrict__ edge_index, int* __restrict__ deg)
{
    const int e = blockIdx.x * 256 + threadIdx.x;
    if (e >= N_EDGES) return;
    atomicAdd(&deg[edge_index[N_EDGES + e]], 1);
}

// ---------------------------------------------------------------------------
// K2a: per-block scan of deg. Writes local exclusive prefix + block sums.
// ---------------------------------------------------------------------------
__global__ __launch_bounds__(256) void scan_local_kernel(
    const int* __restrict__ deg, int* __restrict__ lexcl, int* __restrict__ blocksum)
{
    __shared__ int s[256];
    const int t = threadIdx.x;
    const int gid = blockIdx.x * 256 + t;
    const int v = (gid < N_NODES) ? deg[gid] : 0;
    s[t] = v;
    __syncthreads();
    for (int ofs = 1; ofs < 256; ofs <<= 1) {
        int w = (t >= ofs) ? s[t - ofs] : 0;
        __syncthreads();
        s[t] += w;
        __syncthreads();
    }
    if (gid < N_NODES) lexcl[gid] = s[t] - v;
    if (t == 255) blocksum[blockIdx.x] = s[255];
}

// ---------------------------------------------------------------------------
// K2b: one tiny block scans the 196 block sums -> exclusive block prefixes.
// ---------------------------------------------------------------------------
__global__ __launch_bounds__(256) void scan_top_kernel(
    const int* __restrict__ blocksum, int* __restrict__ blockpref)
{
    __shared__ int s[256];
    const int t = threadIdx.x;
    const int v = (t < SCAN_BLOCKS) ? blocksum[t] : 0;
    s[t] = v;
    __syncthreads();
    for (int ofs = 1; ofs < 256; ofs <<= 1) {
        int w = (t >= ofs) ? s[t - ofs] : 0;
        __syncthreads();
        s[t] += w;
        __syncthreads();
    }
    if (t < SCAN_BLOCKS) blockpref[t] = s[t] - v;
}

// ---------------------------------------------------------------------------
// K2c: offset[i] = cursor[i] = blockpref[block] + lexcl[i]
// ---------------------------------------------------------------------------
__global__ __launch_bounds__(256) void scan_addback_kernel(
    const int* __restrict__ lexcl, const int* __restrict__ blockpref,
    int* __restrict__ offset, int* __restrict__ cursor)
{
    const int gid = blockIdx.x * 256 + threadIdx.x;
    if (gid >= N_NODES) return;
    const int base = blockpref[blockIdx.x] + lexcl[gid];
    offset[gid] = base;
    cursor[gid] = base;
}

// ---------------------------------------------------------------------------
// K3: fused MLP + record write. Records now go out in EDGE order (fully
// coalesced 64-B writes); only an 8-B {edge_id, sender} pair is scattered
// to the CSR slot. Record layout per edge (4 x float4):
//   [ h2*inv6 (6) | y0 (1) | y1 (3) | y2 (5) | sender-as-bits (pad) ]
// ---------------------------------------------------------------------------
__global__ __launch_bounds__(256) void pack_kernel(
    const float* __restrict__ lenght,     // (E, 8)
    const float* __restrict__ edge_attr,  // (E, 9)
    const int*   __restrict__ edge_index, // (2, E)
    const float* __restrict__ fw0,        // (8, 6)
    const float* __restrict__ fw1,        // (6, 6)
    const float* __restrict__ fw2,        // (6, 6)
    int*         __restrict__ cursor,     // (N)
    float4*      __restrict__ rec,        // (E, 4 x float4) edge order
    int2*        __restrict__ es)         // (E) CSR order: {edge_id, sender}
{
    __shared__ float s_w[120];
    for (int i = threadIdx.x; i < 120; i += 256)
        s_w[i] = (i < 48) ? fw0[i] : (i < 84) ? fw1[i - 48] : fw2[i - 84];
    __syncthreads();
    const float* sw0 = s_w;
    const float* sw1 = s_w + 48;
    const float* sw2 = s_w + 84;

    const int e = blockIdx.x * 256 + threadIdx.x;
    if (e >= N_EDGES) return;

    const float inv8 = 0.35355339059327373f;   // 1/sqrt(8)
    const float inv6 = 0.4082482904638631f;    // 1/sqrt(6)

    float len[8];
    const float4 l0 = ((const float4*)(lenght + (long long)e * 8))[0];
    const float4 l1 = ((const float4*)(lenght + (long long)e * 8))[1];
    len[0]=l0.x; len[1]=l0.y; len[2]=l0.z; len[3]=l0.w;
    len[4]=l1.x; len[5]=l1.y; len[6]=l1.z; len[7]=l1.w;

    float h0[6], h1[6], h2[6];
    #pragma unroll
    for (int j = 0; j < 6; ++j) {
        float a = 0.f;
        #pragma unroll
        for (int k = 0; k < 8; ++k) a += len[k] * sw0[k * 6 + j];
        a *= inv8;
        h0[j] = a / (1.f + __expf(-a));
    }
    #pragma unroll
    for (int j = 0; j < 6; ++j) {
        float a = 0.f;
        #pragma unroll
        for (int k = 0; k < 6; ++k) a += h0[k] * sw1[k * 6 + j];
        a *= inv6;
        h1[j] = a / (1.f + __expf(-a));
    }
    #pragma unroll
    for (int j = 0; j < 6; ++j) {
        float a = 0.f;
        #pragma unroll
        for (int k = 0; k < 6; ++k) a += h1[k] * sw2[k * 6 + j];
        a *= inv6;
        h2[j] = a * inv6 / (1.f + __expf(-a));   // fold final-layer 1/sqrt(6)
    }

    const float* ea = edge_attr + (long long)e * 9;
    float y[9];
    #pragma unroll
    for (int i = 0; i < 9; ++i) y[i] = ea[i];

    const int snd = edge_index[e];
    const int r   = edge_index[N_EDGES + e];
    const int p   = atomicAdd(&cursor[r], 1);
    es[p] = make_int2(e, snd);                  // 8-B scatter (was 64-B)

    float4* rp = rec + (long long)e * 4;        // coalesced, edge order
    rp[0] = make_float4(h2[0], h2[1], h2[2], h2[3]);
    rp[1] = make_float4(h2[4], h2[5], y[0], y[1]);
    rp[2] = make_float4(y[2], y[3], y[4], y[5]);
    rp[3] = make_float4(y[6], y[7], y[8], __int_as_float(snd));
}

// ---------------------------------------------------------------------------
// K4: gather + message + segment-sum + node linear. One 64-lane wave / node.
// Half-wave h handles slots j = h, h+2, ... Sender indices come from the
// small es[] array (broadcast loads, prefetched 2+ phases ahead), so the
// node_features gather no longer depends on record arrival. Records and x
// values are double-buffered via an A/B 2-phase unroll (no rotation movs).
// ---------------------------------------------------------------------------
__global__ __launch_bounds__(256) void gather_kernel(
    const float4* __restrict__ rec,          // (E, 4 x float4) edge order
    const float*  __restrict__ node_features,// (N, 32)
    const int2*   __restrict__ es,           // (E) CSR order {eid, snd}
    const int*    __restrict__ offset,       // (N)
    const int*    __restrict__ deg,          // (N)
    const float*  __restrict__ fw3,          // (6, 96)
    const float*  __restrict__ lw0,          // (32, 32)
    const float*  __restrict__ lw1,          // (32, 32)
    const float*  __restrict__ lw2,          // (32, 32)
    float*        __restrict__ out)          // (N, 288)
{
    __shared__ float s_lw0[1024], s_lw1[1024], s_lw2[1024];
    for (int i = threadIdx.x; i < 1024; i += 256) {
        s_lw0[i] = lw0[i];
        s_lw1[i] = lw1[i];
        s_lw2[i] = lw2[i];
    }
    __syncthreads();

    const int wave = threadIdx.x >> 6;
    const int l    = threadIdx.x & 63;
    const int c    = l & 31;
    const int h    = l >> 5;
    const int node = blockIdx.x * 4 + wave;     // 12500 blocks exact

    float f3a[6], f3b[6], f3c[6];
    #pragma unroll
    for (int k = 0; k < 6; ++k) {
        f3a[k] = fw3[k * 96 + c];
        f3b[k] = fw3[k * 96 + 32 + c];
        f3c[k] = fw3[k * 96 + 64 + c];
    }

    const int off = offset[node];
    const int dg  = deg[node];

    float acc[9] = {0.f,0.f,0.f,0.f,0.f,0.f,0.f,0.f,0.f};

    if (dg > h) {
        const int2* esp = es + off;
        const int last = dg - 1;

        // ---- prologue: fill A (slot h) and B (slot h+2) pipelines ----
        int2 eA = esp[min(h,     last)];
        int2 eB = esp[min(h + 2, last)];
        const float4* pa = rec + (long long)eA.x * 4;
        float4 A0 = pa[0], A1 = pa[1], A2 = pa[2], A3 = pa[3];
        float  xA = node_features[(long long)eA.y * CCH + c];
        const float4* pb = rec + (long long)eB.x * 4;
        float4 B0 = pb[0], B1 = pb[1], B2 = pb[2], B3 = pb[3];
        float  xB = node_features[(long long)eB.y * CCH + c];
        eA = esp[min(h + 4, last)];             // es for slot j+4 (A parity)
        eB = esp[min(h + 6, last)];             // es for slot j+6 (B parity)

        int j = h;
        while (true) {
            // ---- A-phase: process slot j ----
            {
                const int eid = eA.x, snd = eA.y;
                eA = esp[min(j + 8, last)];     // refill es pipe (depth 2)
                const float w0c = A0.x*f3a[0] + A0.y*f3a[1] + A0.z*f3a[2]
                                + A0.w*f3a[3] + A1.x*f3a[4] + A1.y*f3a[5];
                const float w1c = A0.x*f3b[0] + A0.y*f3b[1] + A0.z*f3b[2]
                                + A0.w*f3b[3] + A1.x*f3b[4] + A1.y*f3b[5];
                const float w2c = A0.x*f3c[0] + A0.y*f3c[1] + A0.z*f3c[2]
                                + A0.w*f3c[3] + A1.x*f3c[4] + A1.y*f3c[5];
                const float x = xA;
                acc[0] += (w0c * x) * A1.z;
                const float a1 = w1c * x;
                acc[1] += a1 * A1.w;
                acc[2] += a1 * A2.x;
                acc[3] += a1 * A2.y;
                const float a2 = w2c * x;
                acc[4] += a2 * A2.z;
                acc[5] += a2 * A2.w;
                acc[6] += a2 * A3.x;
                acc[7] += a2 * A3.y;
                acc[8] += a2 * A3.z;
                // refill A buffers for slot j+4 (clamped loads are harmless)
                const float4* rp = rec + (long long)eid * 4;
                A0 = rp[0]; A1 = rp[1]; A2 = rp[2]; A3 = rp[3];
                xA = node_features[(long long)snd * CCH + c];
            }
            j += 2;
            if (j >= dg) break;
            // ---- B-phase: process slot j ----
            {
                const int eid = eB.x, snd = eB.y;
                eB = esp[min(j + 8, last)];
                const float w0c = B0.x*f3a[0] + B0.y*f3a[1] + B0.z*f3a[2]
                                + B0.w*f3a[3] + B1.x*f3a[4] + B1.y*f3a[5];
                const float w1c = B0.x*f3b[0] + B0.y*f3b[1] + B0.z*f3b[2]
                                + B0.w*f3b[3] + B1.x*f3b[4] + B1.y*f3b[5];
                const float w2c = B0.x*f3c[0] + B0.y*f3c[1] + B0.z*f3c[2]
                                + B0.w*f3c[3] + B1.x*f3c[4] + B1.y*f3c[5];
                const float x = xB;
                acc[0] += (w0c * x) * B1.z;
                const float a1 = w1c * x;
                acc[1] += a1 * B1.w;
                acc[2] += a1 * B2.x;
                acc[3] += a1 * B2.y;
                const float a2 = w2c * x;
                acc[4] += a2 * B2.z;
                acc[5] += a2 * B2.w;
                acc[6] += a2 * B3.x;
                acc[7] += a2 * B3.y;
                acc[8] += a2 * B3.z;
                const float4* rp = rec + (long long)eid * 4;
                B0 = rp[0]; B1 = rp[1]; B2 = rp[2]; B3 = rp[3];
                xB = node_features[(long long)snd * CCH + c];
            }
            j += 2;
            if (j >= dg) break;
        }
    }

    // combine halves: lanes 0..31 hold msg[c][0..8]
    #pragma unroll
    for (int k = 0; k < 9; ++k) acc[k] += __shfl_down(acc[k], 32);

    // node linear via shfl transpose; lane d = c, halves split the cc loop
    const int d = c;
    float o0 = 0.f;
    float o1[3] = {0.f, 0.f, 0.f};
    float o2[5] = {0.f, 0.f, 0.f, 0.f, 0.f};
    for (int cc = h * 16; cc < h * 16 + 16; ++cc) {
        const float m0 = __shfl(acc[0], cc);
        const float m1 = __shfl(acc[1], cc);
        const float m2 = __shfl(acc[2], cc);
        const float m3 = __shfl(acc[3], cc);
        const float m4 = __shfl(acc[4], cc);
        const float m5 = __shfl(acc[5], cc);
        const float m6 = __shfl(acc[6], cc);
        const float m7 = __shfl(acc[7], cc);
        const float m8 = __shfl(acc[8], cc);
        o0 += m0 * s_lw0[cc * 32 + d];
        const float w1 = s_lw1[cc * 32 + d];
        o1[0] += m1 * w1; o1[1] += m2 * w1; o1[2] += m3 * w1;
        const float w2 = s_lw2[cc * 32 + d];
        o2[0] += m4 * w2; o2[1] += m5 * w2; o2[2] += m6 * w2;
        o2[3] += m7 * w2; o2[4] += m8 * w2;
    }

    o0 += __shfl_down(o0, 32);
    #pragma unroll
    for (int i = 0; i < 3; ++i) o1[i] += __shfl_down(o1[i], 32);
    #pragma unroll
    for (int i = 0; i < 5; ++i) o2[i] += __shfl_down(o2[i], 32);

    if (h == 0) {
        const float inv32 = 0.17677669529663687f;  // 1/sqrt(32)
        float* op = out + (long long)node * ROW;
        op[d] = o0 * inv32;
        #pragma unroll
        for (int i = 0; i < 3; ++i) op[32 + d * 3 + i] = o1[i] * inv32;
        #pragma unroll
        for (int i = 0; i < 5; ++i) op[128 + d * 5 + i] = o2[i] * inv32;
    }
}

extern "C" void kernel_launch(void* const* d_in, const int* in_sizes, int n_in,
                              void* d_out, int out_size, void* d_ws, size_t ws_size,
                              hipStream_t stream)
{
    const float* lenght = (const float*)d_in[0];
    const float* nf     = (const float*)d_in[1];
    const float* ea     = (const float*)d_in[2];
    const int*   ei     = (const int*)d_in[3];
    const float* fw0    = (const float*)d_in[4];
    const float* fw1    = (const float*)d_in[5];
    const float* fw2    = (const float*)d_in[6];
    const float* fw3    = (const float*)d_in[7];
    const float* lw0    = (const float*)d_in[8];
    const float* lw1    = (const float*)d_in[9];
    const float* lw2    = (const float*)d_in[10];
    float* out = (float*)d_out;

    // workspace layout
    char* ws = (char*)d_ws;
    float4* rec    = (float4*)ws; ws += (size_t)N_EDGES * 4 * sizeof(float4);  // 64 MB
    int2* es       = (int2*)ws;   ws += (size_t)N_EDGES * sizeof(int2);        //  8 MB
    int* deg       = (int*)ws;    ws += (size_t)N_NODES * sizeof(int);
    int* offset    = (int*)ws;    ws += (size_t)N_NODES * sizeof(int);
    int* cursor    = (int*)ws;    ws += (size_t)N_NODES * sizeof(int);
    int* lexcl     = (int*)ws;    ws += (size_t)N_NODES * sizeof(int);
    int* blocksum  = (int*)ws;    ws += (size_t)SCAN_BLOCKS * sizeof(int);
    int* blockpref = (int*)ws;    ws += (size_t)SCAN_BLOCKS * sizeof(int);

    hipMemsetAsync(deg, 0, (size_t)N_NODES * sizeof(int), stream);

    const int EB = (N_EDGES + 255) / 256;
    hist_kernel        <<<EB, 256, 0, stream>>>(ei, deg);
    scan_local_kernel  <<<SCAN_BLOCKS, 256, 0, stream>>>(deg, lexcl, blocksum);
    scan_top_kernel    <<<1, 256, 0, stream>>>(blocksum, blockpref);
    scan_addback_kernel<<<SCAN_BLOCKS, 256, 0, stream>>>(lexcl, blockpref, offset, cursor);
    pack_kernel        <<<EB, 256, 0, stream>>>(lenght, ea, ei, fw0, fw1, fw2, cursor, rec, es);
    gather_kernel      <<<N_NODES / 4, 256, 0, stream>>>(
        rec, nf, es, offset, deg, fw3, lw0, lw1, lw2, out);
}